// Round 1
// baseline (232.807 us; speedup 1.0000x reference)
//
#include <hip/hip_runtime.h>

typedef __bf16 bf16;
typedef bf16 bf16x8 __attribute__((ext_vector_type(8)));
typedef float f32x4 __attribute__((ext_vector_type(4)));

#define PTS 16       // points per block
#define WPITCH 200   // bf16 elems per W row (192 + 8 pad) -> 400B row stride
#define TPITCH 200

// LDS budget: W 64*200*2 = 25600 B, T 48*200*2 = 19200 B, Y 16*192*4 = 12288 B
// total ~57 KB -> 2 blocks/CU (8 waves/CU)

__global__ __launch_bounds__(256, 2)
void affine_linear_fused(const float* __restrict__ X, const float* __restrict__ J,
                         const float* __restrict__ A, const float* __restrict__ Bm,
                         const float* __restrict__ C, float* __restrict__ Y)
{
    __shared__ __attribute__((aligned(16))) bf16 W_lds[64 * WPITCH];
    __shared__ __attribute__((aligned(16))) bf16 T_lds[48 * TPITCH];
    __shared__ __attribute__((aligned(16))) float Y_lds[PTS * 192];

    const int tid  = threadIdx.x;
    const int wave = tid >> 6;
    const int lane = tid & 63;
    const long bn0 = (long)blockIdx.x * PTS;

    // ---- Stage W = [A | Bm | C] into LDS as bf16, row = f, K order = [a|b|c]x64 ----
    for (int idx = tid; idx < 4096; idx += 256) {
        int f = idx >> 6, d = idx & 63;
        bf16* row = &W_lds[f * WPITCH];
        row[d]       = (bf16)A[idx];
        row[64 + d]  = (bf16)Bm[idx];
        row[128 + d] = (bf16)C[idx];
    }

    // ---- Terms: wave w handles points 4w+q (q=0..3), lane = channel d ----
    for (int q = 0; q < 4; ++q) {
        int p = wave * 4 + q;
        long bn = bn0 + p;
        const float* Jc = J + (bn * 64 + lane) * 6;
        const float* Xc = X + (bn * 64 + lane) * 3;
        float a1x = Jc[0], a2x = Jc[1];
        float a1y = Jc[2], a2y = Jc[3];
        float a1z = Jc[4], a2z = Jc[5];
        float xx = Xc[0], xy = Xc[1], xz = Xc[2];

        float n1   = sqrtf(a1x*a1x + a1y*a1y + a1z*a1z);
        float inv1 = 1.0f / fmaxf(n1, 1e-12f);
        float b1x = a1x*inv1, b1y = a1y*inv1, b1z = a1z*inv1;
        float dot = b1x*a2x + b1y*a2y + b1z*a2z;
        float ux = a2x - dot*b1x, uy = a2y - dot*b1y, uz = a2z - dot*b1z;
        float n2   = sqrtf(ux*ux + uy*uy + uz*uz);
        float inv2 = 1.0f / fmaxf(n2, 1e-12f);
        float b2x = ux*inv2, b2y = uy*inv2, b2z = uz*inv2;
        float b3x = b1y*b2z - b1z*b2y;
        float b3y = b1z*b2x - b1x*b2z;
        float b3z = b1x*b2y - b1y*b2x;

        float rt0 = b1x*xx + b1y*xy + b1z*xz;
        float rt1 = b2x*xx + b2y*xy + b2z*xz;
        float rt2 = b3x*xx + b3y*xy + b3z*xz;

        float at0 = b1x*rt0 + b2x*rt1;   // a_term, component i over {x,y,z}
        float at1 = b1y*rt0 + b2y*rt1;
        float at2 = b1z*rt0 + b2z*rt1;
        float bt0 = b2x*rt0 - b1x*rt1;   // b_term
        float bt1 = b2y*rt0 - b1y*rt1;
        float bt2 = b2z*rt0 - b1z*rt1;
        float ct0 = b3x*rt2, ct1 = b3y*rt2, ct2 = b3z*rt2;  // c_term

        // T rows m = p*3 + i ; K index e = {0:a,1:b,2:c}*64 + d
        bf16* r0 = &T_lds[(p*3 + 0) * TPITCH];
        bf16* r1 = &T_lds[(p*3 + 1) * TPITCH];
        bf16* r2 = &T_lds[(p*3 + 2) * TPITCH];
        r0[lane] = (bf16)at0; r0[64+lane] = (bf16)bt0; r0[128+lane] = (bf16)ct0;
        r1[lane] = (bf16)at1; r1[64+lane] = (bf16)bt1; r1[128+lane] = (bf16)ct1;
        r2[lane] = (bf16)at2; r2[64+lane] = (bf16)bt2; r2[128+lane] = (bf16)ct2;
    }
    __syncthreads();

    // ---- MFMA: D[m, f] = sum_e T[m,e] * W[f,e]; wave owns f-tile = wave*16 ----
    const int l16 = lane & 15;
    const int lq  = lane >> 4;       // quad 0..3
    const bf16* brow = &W_lds[(wave*16 + l16) * WPITCH + lq*8];
    for (int mt = 0; mt < 3; ++mt) {
        f32x4 acc = {0.f, 0.f, 0.f, 0.f};
        const bf16* arow = &T_lds[(mt*16 + l16) * TPITCH + lq*8];
        #pragma unroll
        for (int kk = 0; kk < 6; ++kk) {
            bf16x8 af = *(const bf16x8*)(arow + kk*32);
            bf16x8 bfr = *(const bf16x8*)(brow + kk*32);
            acc = __builtin_amdgcn_mfma_f32_16x16x32_bf16(af, bfr, acc, 0, 0, 0);
        }
        // C/D layout: col = lane&15 (f), row = (lane>>4)*4 + r  (m = p*3+i)
        int fcol = wave*16 + l16;
        #pragma unroll
        for (int r = 0; r < 4; ++r) {
            int m = mt*16 + lq*4 + r;
            int p = m / 3, i = m - p*3;
            Y_lds[p*192 + fcol*3 + i] = acc[r];
        }
    }
    __syncthreads();

    // ---- Coalesced write-out: 16 points x 192 floats ----
    const f32x4* Ysrc = (const f32x4*)Y_lds;
    f32x4* Ydst = (f32x4*)(Y + bn0 * 192);
    #pragma unroll
    for (int idx = tid; idx < PTS*192/4; idx += 256) {
        Ydst[idx] = Ysrc[idx];
    }
}

extern "C" void kernel_launch(void* const* d_in, const int* in_sizes, int n_in,
                              void* d_out, int out_size, void* d_ws, size_t ws_size,
                              hipStream_t stream) {
    const float* X  = (const float*)d_in[0];
    const float* J  = (const float*)d_in[1];
    const float* A  = (const float*)d_in[2];
    const float* Bm = (const float*)d_in[3];
    const float* C  = (const float*)d_in[4];
    float* Y = (float*)d_out;

    const int points = in_sizes[0] / (64 * 3);   // B*N = 65536
    const int blocks = points / PTS;             // 4096
    affine_linear_fused<<<blocks, 256, 0, stream>>>(X, J, A, Bm, C, Y);
}

// Round 2
// 203.684 us; speedup vs baseline: 1.1430x; 1.1430x over previous
//
#include <hip/hip_runtime.h>

typedef __bf16 bf16;
typedef bf16 bf16x8 __attribute__((ext_vector_type(8)));
typedef float f32x4 __attribute__((ext_vector_type(4)));

#define PTS 16       // points per block
#define TPITCH 200   // bf16 elems per T row (192 + 8 pad) -> 400B row stride, 16B aligned

// LDS: T 48*200*2 = 19200 B, reused as fp32 Y staging (12288 B) after MFMA.
// 4 blocks/CU (launch_bounds 256,4) -> 16 waves/CU.

__global__ __launch_bounds__(256, 4)
void affine_linear_fused(const float* __restrict__ X, const float* __restrict__ J,
                         const float* __restrict__ A, const float* __restrict__ Bm,
                         const float* __restrict__ C, float* __restrict__ Y)
{
    __shared__ __attribute__((aligned(16))) bf16 T_lds[48 * TPITCH];

    const int tid  = threadIdx.x;
    const int wave = tid >> 6;
    const int lane = tid & 63;
    const int l16  = lane & 15;
    const int lq   = lane >> 4;       // quad 0..3
    const long bn0 = (long)blockIdx.x * PTS;

    // ---- B-fragments from global (same for all blocks; L2/L3-hot). ----
    // W[f, k]: f = wave*16+l16 row; k = kk*32 + lq*8 + j; segments: kk<2:A, <4:Bm, else C
    const int f = wave * 16 + l16;
    bf16x8 wfrag[6];
    #pragma unroll
    for (int kk = 0; kk < 6; ++kk) {
        const float* src = (kk < 2) ? A : (kk < 4) ? Bm : C;
        const f32x4* p4 = (const f32x4*)(src + f * 64 + (kk & 1) * 32 + lq * 8);
        f32x4 lo = p4[0], hi = p4[1];
        bf16x8 w;
        w[0] = (bf16)lo[0]; w[1] = (bf16)lo[1]; w[2] = (bf16)lo[2]; w[3] = (bf16)lo[3];
        w[4] = (bf16)hi[0]; w[5] = (bf16)hi[1]; w[6] = (bf16)hi[2]; w[7] = (bf16)hi[3];
        wfrag[kk] = w;
    }

    // ---- Issue all J/X loads for this wave's 4 points up front (ILP) ----
    float j0[4], j1[4], j2[4], j3[4], j4[4], j5[4];
    float x0[4], x1[4], x2[4];
    #pragma unroll
    for (int q = 0; q < 4; ++q) {
        long bn = bn0 + wave * 4 + q;
        const float* Jc = J + (bn * 64 + lane) * 6;
        const float* Xc = X + (bn * 64 + lane) * 3;
        float2 ja = *(const float2*)(Jc + 0);
        float2 jb = *(const float2*)(Jc + 2);
        float2 jc = *(const float2*)(Jc + 4);
        j0[q] = ja.x; j1[q] = ja.y;
        j2[q] = jb.x; j3[q] = jb.y;
        j4[q] = jc.x; j5[q] = jc.y;
        x0[q] = Xc[0]; x1[q] = Xc[1]; x2[q] = Xc[2];
    }

    // ---- Terms: wave w handles points 4w+q, lane = channel d ----
    #pragma unroll
    for (int q = 0; q < 4; ++q) {
        int p = wave * 4 + q;
        float a1x = j0[q], a2x = j1[q];
        float a1y = j2[q], a2y = j3[q];
        float a1z = j4[q], a2z = j5[q];
        float xx = x0[q], xy = x1[q], xz = x2[q];

        float n1   = sqrtf(a1x*a1x + a1y*a1y + a1z*a1z);
        float inv1 = 1.0f / fmaxf(n1, 1e-12f);
        float b1x = a1x*inv1, b1y = a1y*inv1, b1z = a1z*inv1;
        float dot = b1x*a2x + b1y*a2y + b1z*a2z;
        float ux = a2x - dot*b1x, uy = a2y - dot*b1y, uz = a2z - dot*b1z;
        float n2   = sqrtf(ux*ux + uy*uy + uz*uz);
        float inv2 = 1.0f / fmaxf(n2, 1e-12f);
        float b2x = ux*inv2, b2y = uy*inv2, b2z = uz*inv2;
        float b3x = b1y*b2z - b1z*b2y;
        float b3y = b1z*b2x - b1x*b2z;
        float b3z = b1x*b2y - b1y*b2x;

        float rt0 = b1x*xx + b1y*xy + b1z*xz;
        float rt1 = b2x*xx + b2y*xy + b2z*xz;
        float rt2 = b3x*xx + b3y*xy + b3z*xz;

        float at0 = b1x*rt0 + b2x*rt1;
        float at1 = b1y*rt0 + b2y*rt1;
        float at2 = b1z*rt0 + b2z*rt1;
        float bt0 = b2x*rt0 - b1x*rt1;
        float bt1 = b2y*rt0 - b1y*rt1;
        float bt2 = b2z*rt0 - b1z*rt1;
        float ct0 = b3x*rt2, ct1 = b3y*rt2, ct2 = b3z*rt2;

        bf16* r0 = &T_lds[(p*3 + 0) * TPITCH];
        bf16* r1 = &T_lds[(p*3 + 1) * TPITCH];
        bf16* r2 = &T_lds[(p*3 + 2) * TPITCH];
        r0[lane] = (bf16)at0; r0[64+lane] = (bf16)bt0; r0[128+lane] = (bf16)ct0;
        r1[lane] = (bf16)at1; r1[64+lane] = (bf16)bt1; r1[128+lane] = (bf16)ct1;
        r2[lane] = (bf16)at2; r2[64+lane] = (bf16)bt2; r2[128+lane] = (bf16)ct2;
    }
    __syncthreads();

    // ---- MFMA: D[m, f] = sum_k T[m,k] * W[f,k]; all 3 m-tiles to registers ----
    f32x4 acc[3];
    #pragma unroll
    for (int mt = 0; mt < 3; ++mt) {
        f32x4 a = {0.f, 0.f, 0.f, 0.f};
        const bf16* arow = &T_lds[(mt*16 + l16) * TPITCH + lq*8];
        #pragma unroll
        for (int kk = 0; kk < 6; ++kk) {
            bf16x8 af = *(const bf16x8*)(arow + kk*32);
            a = __builtin_amdgcn_mfma_f32_16x16x32_bf16(af, wfrag[kk], a, 0, 0, 0);
        }
        acc[mt] = a;
    }
    __syncthreads();   // all waves done reading T_lds -> safe to reuse as Y staging

    // ---- Scatter C-fragments into fp32 Y staging (union with T_lds) ----
    float* Y_lds = (float*)T_lds;
    #pragma unroll
    for (int mt = 0; mt < 3; ++mt) {
        #pragma unroll
        for (int r = 0; r < 4; ++r) {
            int m = mt*16 + lq*4 + r;     // m = p*3 + i
            int p = m / 3, i = m - p*3;
            Y_lds[p*192 + f*3 + i] = acc[mt][r];
        }
    }
    __syncthreads();

    // ---- Coalesced write-out: 16 points x 192 floats ----
    const f32x4* Ysrc = (const f32x4*)Y_lds;
    f32x4* Ydst = (f32x4*)(Y + bn0 * 192);
    #pragma unroll
    for (int idx = tid; idx < PTS*192/4; idx += 256) {
        Ydst[idx] = Ysrc[idx];
    }
}

extern "C" void kernel_launch(void* const* d_in, const int* in_sizes, int n_in,
                              void* d_out, int out_size, void* d_ws, size_t ws_size,
                              hipStream_t stream) {
    const float* X  = (const float*)d_in[0];
    const float* J  = (const float*)d_in[1];
    const float* A  = (const float*)d_in[2];
    const float* Bm = (const float*)d_in[3];
    const float* C  = (const float*)d_in[4];
    float* Y = (float*)d_out;

    const int points = in_sizes[0] / (64 * 3);   // B*N = 65536
    const int blocks = points / PTS;             // 4096
    affine_linear_fused<<<blocks, 256, 0, stream>>>(X, J, A, Bm, C, Y);
}